// Round 9
// baseline (157.636 us; speedup 1.0000x reference)
//
#include <hip/hip_runtime.h>

// NeRF fused kernel for MI355X (gfx950) — round 14.
// Round 13 post-mortem: setprio = no win (106.0 vs best-known 102.6; m190
// says it hurts lockstep GEMM loops) -> dropped. Model of main (~40us vs
// 18.6us MFMA floor): per-SIMD MFMA 18.6us + VALU ~14us + LDS ~10us barely
// overlap (MfmaUtil 37 + VALUBusy 36 + ~27% waitcnt). The structurally
// removable stall: rolled ks3 loop re-opens every iteration with a
// ~120-200cyc lgkmcnt stall (iter i+1's first ds_reads issue after iter i's
// pack). Round 14 = round-8 config EXACT (36-block setup, no rotation, no
// setprio) + 1-deep cross-iteration prefetch: load next iter's wA0/wB0/w3k
// into regs BEFORE the pack, so their latency hides under pack+phase3.
// +24 VGPR (64 -> ~90) under the (512,4) cap of 128 — round-9's intent
// without round-9's spill. Math untouched -> absmax bit-identical.
// Permutation identity (HW-verified rounds 4-13):
//   h2 feature(slot) = 32*quad + mt*4 + r  (phase-2 D)  =  32*quad + ks3*8 + j
//   (phase-3 B), so phase-2 output regs ARE phase-3 B-frags.

typedef _Float16 f16;
typedef __attribute__((ext_vector_type(2))) _Float16 h2v;
typedef __attribute__((ext_vector_type(8))) _Float16 half8;
typedef __attribute__((ext_vector_type(4))) float floatx4;

#define H 128
#define NS 64

static __device__ __forceinline__ h2v pkrtz(float a, float b) {
  return __builtin_bit_cast(h2v, __builtin_amdgcn_cvt_pkrtz(a, b));
}

// x += dpp_shifted(x) with 0-fill; CTRL/RM compile-time (builtin needs ICE).
template <int CTRL, int RM>
static __device__ __forceinline__ float dpp_add(float x) {
  int sh = __builtin_amdgcn_update_dpp(0, __builtin_bit_cast(int, x),
                                       CTRL, RM, 0xf, false);
  return x + __builtin_bit_cast(float, sh);
}

// Wave64 inclusive add-scan, pure VALU (classic gfx9 sequence).
static __device__ __forceinline__ float wave_iscan(float x) {
  x = dpp_add<0x111, 0xf>(x);   // row_shr:1
  x = dpp_add<0x112, 0xf>(x);   // row_shr:2
  x = dpp_add<0x114, 0xf>(x);   // row_shr:4
  x = dpp_add<0x118, 0xf>(x);   // row_shr:8
  x = dpp_add<0x142, 0xa>(x);   // row_bcast:15 -> rows 1,3
  x = dpp_add<0x143, 0xc>(x);   // row_bcast:31 -> rows 2,3
  return x;
}

// ---------------------------------------------------------------------------
// Setup (round-8 version verbatim — part of the 102.6us-proven config):
// W2 -> A-frags with permuted cols n = 32*(l16>>2) + mt*4 + (l16&3);
// W3 -> A-frags with matching permuted rows k3 = 32*(lane>>4) + ks*8 + j
// (cols padded to 16). 36 blocks x 256 threads, direct scattered gathers.
// ---------------------------------------------------------------------------
__global__ void nerf_setup(const float* __restrict__ W2, const float* __restrict__ W3,
                           f16* __restrict__ wsW2, f16* __restrict__ wsW3) {
  int t = blockIdx.x * blockDim.x + threadIdx.x;
  if (t < 8192) {                       // W2 frags
    int j2 = t & 3, lane = (t >> 2) & 63, mt = (t >> 8) & 7, ks = t >> 11;
    int l16 = lane & 15;
    int k = ks * 32 + ((lane >> 4) * 8) + 2 * j2;
    int n = 32 * (l16 >> 2) + mt * 4 + (l16 & 3);    // permuted column
    wsW2[2 * t]     = (f16)W2[k * H + n];
    wsW2[2 * t + 1] = (f16)W2[(k + 1) * H + n];
  } else if (t < 9216) {                // W3 frags (A-layout, permuted rows, padded)
    int u = t - 8192;
    int j2 = u & 3, lane = (u >> 2) & 63, ks = u >> 8;
    int c = lane & 15;
    int k3 = 32 * (lane >> 4) + ks * 8 + 2 * j2;     // permuted h2 feature
    wsW3[2 * u]     = (c < 4) ? (f16)W3[k3 * 4 + c]       : (f16)0.0f;
    wsW3[2 * u + 1] = (c < 4) ? (f16)W3[(k3 + 1) * 4 + c] : (f16)0.0f;
  }
}

// ---------------------------------------------------------------------------
// Main: block = 8 rays = 8 waves; wave = 1 ray = 64 points.
// One barrier (after LDS weight staging); no other cross-wave deps.
// ---------------------------------------------------------------------------
__global__ __launch_bounds__(512, 4) void nerf_main(
    const float* __restrict__ origins, const float* __restrict__ dirs,
    const float* __restrict__ W1, const float* __restrict__ b1,
    const float* __restrict__ b2, const float* __restrict__ b3,
    const f16* __restrict__ ws,          // wsW2 (32 KB) ++ wsW3 (4 KB)
    float* __restrict__ out)
{
  __shared__ __align__(16) half8 w_lds[2304];     // 36 KB: W2 frags [0..2047], W3 [2048..2303]
  __shared__ __align__(16) float b2_lds[H];       // 512 B
  __shared__ __align__(16) f16   popd[8][2][H];   // per-wave po/pd strips (4 KB)
  __shared__ __align__(16) float f_lds[8][64][4]; // render transpose (8 KB)

  const int t = threadIdx.x;
  const int w = t >> 6, lane = t & 63, quad = lane >> 4, l16 = lane & 15;
  const float delta = 4.0f / NS;       // near=2, far=6 baked
  const int ray = blockIdx.x * 8 + w;

  // ---- Stage weights into LDS (2304 x 16 B = 4.5 per thread) ----
  {
    const uint4* src = (const uint4*)ws;
    uint4* dst = (uint4*)w_lds;
    #pragma unroll
    for (int i = 0; i < 4; ++i) dst[t + i * 512] = src[t + i * 512];
    if (t < 256) dst[t + 2048] = src[t + 2048];
    if (t < 32)  ((float4*)b2_lds)[t] = ((const float4*)b2)[t];
  }

  // ---- po/pd: po[k] = o@W1[:,k]+b1[k], pd[k] = d@W1[:,k]; f16 to LDS ----
  {
    const float o0 = origins[ray*3], o1 = origins[ray*3+1], o2 = origins[ray*3+2];
    const float d0 = dirs[ray*3],    d1 = dirs[ray*3+1],    d2 = dirs[ray*3+2];
    const int k0 = lane * 2;
    const float2 wr0 = *(const float2*)&W1[0*H + k0];
    const float2 wr1 = *(const float2*)&W1[1*H + k0];
    const float2 wr2 = *(const float2*)&W1[2*H + k0];
    const float2 bb  = *(const float2*)&b1[k0];
    float poa = fmaf(o2, wr2.x, fmaf(o1, wr1.x, fmaf(o0, wr0.x, bb.x)));
    float pob = fmaf(o2, wr2.y, fmaf(o1, wr1.y, fmaf(o0, wr0.y, bb.y)));
    float pda = fmaf(d2, wr2.x, fmaf(d1, wr1.x, d0 * wr0.x));
    float pdb = fmaf(d2, wr2.y, fmaf(d1, wr1.y, d0 * wr0.y));
    h2v po2; po2[0] = (f16)poa; po2[1] = (f16)pob;
    h2v pd2; pd2[0] = (f16)pda; pd2[1] = (f16)pdb;
    *(h2v*)&popd[w][0][k0] = po2;
    *(h2v*)&popd[w][1][k0] = pd2;
  }

  // ---- hb precompute: hb[ks2][tr] = relu(po + m*pd), resident 64 VGPRs ----
  // m exact in f16 (multiple of 1/32); sample s = tr*16 + l16.
  half8 hb[4][4];
  {
    const half8 z8 = (half8)(f16)0.0f;
    half8 m8[4];
    #pragma unroll
    for (int tr = 0; tr < 4; ++tr)
      m8[tr] = (half8)(f16)(2.0f + (tr*16 + l16 + 0.5f) * delta);
    #pragma unroll
    for (int ks = 0; ks < 4; ++ks) {
      const half8 po8 = *(const half8*)&popd[w][0][ks*32 + quad*8];
      const half8 pd8 = *(const half8*)&popd[w][1][ks*32 + quad*8];
      #pragma unroll
      for (int tr = 0; tr < 4; ++tr)
        hb[ks][tr] = __builtin_elementwise_max(pd8 * m8[tr] + po8, z8);
    }
  }

  __syncthreads();                       // weights staged

  const half8* w2f = w_lds;              // 2048 frags
  const half8* w3f = w_lds + 2048;       // 256 frags
  const h2v z2 = (h2v)(f16)0.0f;

  // acc3 init = b3 broadcast (quad 0 rows are the only consumed ones; W3
  // cols >=4 are zero-padded so other quads are garbage-but-unused).
  floatx4 acc3[4];
  {
    const float4 b3v = *(const float4*)&b3[0];
    #pragma unroll
    for (int tr = 0; tr < 4; ++tr) {
      acc3[tr][0] = b3v.x; acc3[tr][1] = b3v.y;
      acc3[tr][2] = b3v.z; acc3[tr][3] = b3v.w;
    }
  }

  // ---- Fused phase 2+3, mt-pair outer, ROLLED (4 iters) with 1-deep
  // cross-iteration operand prefetch: next iter's wA(ks2=0)/wB(ks2=0)/w3k
  // are loaded into regs BEFORE this iter's pack, so their LDS latency
  // hides under pack+phase3 and the next iter's first MFMA doesn't stall
  // on the loop backedge. +24 VGPR, well under the (512,4) cap of 128. ----
  half8 pA  = w2f[lane];                 // ks3=0: (ks2=0, mt0=0)
  half8 pB  = w2f[64 + lane];            // ks3=0: (ks2=0, mt1=1)
  half8 pW3 = w3f[lane];                 // ks3=0 w3k
  #pragma unroll 1
  for (int ks3 = 0; ks3 < 4; ++ks3) {
    const int mt0 = 2 * ks3, mt1 = mt0 + 1;
    // bias fold: acc[mt][tr][r] starts at b2[32*quad + 4*mt + r]
    const float4 bA = *(const float4*)&b2_lds[quad*32 + ks3*8];
    const float4 bB = *(const float4*)&b2_lds[quad*32 + ks3*8 + 4];
    const half8 w3k = pW3;
    floatx4 accA[4], accB[4];
    #pragma unroll
    for (int tr = 0; tr < 4; ++tr) {
      accA[tr][0] = bA.x; accA[tr][1] = bA.y; accA[tr][2] = bA.z; accA[tr][3] = bA.w;
      accB[tr][0] = bB.x; accB[tr][1] = bB.y; accB[tr][2] = bB.z; accB[tr][3] = bB.w;
    }
    // ks2 = 0 uses prefetched operands (no LDS wait at iter start)
    #pragma unroll
    for (int tr = 0; tr < 4; ++tr) {
      accA[tr] = __builtin_amdgcn_mfma_f32_16x16x32_f16(pA, hb[0][tr], accA[tr], 0, 0, 0);
      accB[tr] = __builtin_amdgcn_mfma_f32_16x16x32_f16(pB, hb[0][tr], accB[tr], 0, 0, 0);
    }
    #pragma unroll
    for (int ks2 = 1; ks2 < 4; ++ks2) {
      const half8 wA = w2f[(ks2*8 + mt0)*64 + lane];
      const half8 wB = w2f[(ks2*8 + mt1)*64 + lane];
      #pragma unroll
      for (int tr = 0; tr < 4; ++tr) {
        accA[tr] = __builtin_amdgcn_mfma_f32_16x16x32_f16(wA, hb[ks2][tr], accA[tr], 0, 0, 0);
        accB[tr] = __builtin_amdgcn_mfma_f32_16x16x32_f16(wB, hb[ks2][tr], accB[tr], 0, 0, 0);
      }
    }
    // issue next iter's prefetch BEFORE the pack (latency hides under it)
    if (ks3 < 3) {
      pA  = w2f[(mt0 + 2)*64 + lane];    // next ks3: (ks2=0, mt0+2)
      pB  = w2f[(mt1 + 2)*64 + lane];
      pW3 = w3f[(ks3 + 1)*64 + lane];
    }
    // pack (bias already in acc) + phase-3 MFMA; b covers features
    // 32*quad + 8*ks3 + 0..7 matching W3's permuted rows.
    #pragma unroll
    for (int tr = 0; tr < 4; ++tr) {
      h2v c0 = __builtin_elementwise_max(pkrtz(accA[tr][0], accA[tr][1]), z2);
      h2v c1 = __builtin_elementwise_max(pkrtz(accA[tr][2], accA[tr][3]), z2);
      h2v c2 = __builtin_elementwise_max(pkrtz(accB[tr][0], accB[tr][1]), z2);
      h2v c3 = __builtin_elementwise_max(pkrtz(accB[tr][2], accB[tr][3]), z2);
      half8 b = { c0[0], c0[1], c1[0], c1[1], c2[0], c2[1], c3[0], c3[1] };
      acc3[tr] = __builtin_amdgcn_mfma_f32_16x16x32_f16(w3k, b, acc3[tr], 0, 0, 0);
    }
  }

  // D3: lane holds f[m = quad*4+r][point tr*16+l16]; quad 0 rows 0..3 are
  // (R,G,B,sigma), b3 already folded in. Transpose via tiny f_lds (same
  // wave, no barrier).
  if (quad == 0) {
    #pragma unroll
    for (int tr = 0; tr < 4; ++tr) {
      float4 fv;
      fv.x = acc3[tr][0]; fv.y = acc3[tr][1];
      fv.z = acc3[tr][2]; fv.w = acc3[tr][3];
      *(float4*)&f_lds[w][tr*16 + l16][0] = fv;      // ds_write_b128
    }
  }

  // ---- Phase 4: volume rendering, lane = sample; DPP scan, no bpermute ----
  {
    const float4 fv = *(const float4*)&f_lds[w][lane][0];
    const float sigma = fv.w;
    const float alpha = 1.0f - __expf(-sigma * delta);
    const float S  = wave_iscan(sigma);              // inclusive prefix
    const float T  = __expf(-delta * (S - sigma));   // exclusive transmittance
    const float wt = alpha * T;
    const float sr = wave_iscan(wt * fv.x);          // lane 63 = total
    const float sg = wave_iscan(wt * fv.y);
    const float sb = wave_iscan(wt * fv.z);
    if (lane == 63) {
      out[ray*3+0] = sr; out[ray*3+1] = sg; out[ray*3+2] = sb;
    }
  }
}

extern "C" void kernel_launch(void* const* d_in, const int* in_sizes, int n_in,
                              void* d_out, int out_size, void* d_ws, size_t ws_size,
                              hipStream_t stream) {
  const float* origins = (const float*)d_in[0];
  const float* dirs    = (const float*)d_in[1];
  const float* W1      = (const float*)d_in[2];
  const float* b1      = (const float*)d_in[3];
  const float* W2      = (const float*)d_in[4];
  const float* b2      = (const float*)d_in[5];
  const float* W3      = (const float*)d_in[6];
  const float* b3      = (const float*)d_in[7];
  float* out = (float*)d_out;

  f16* wsW2 = (f16*)d_ws;          // 16384 f16 = 32 KB
  f16* wsW3 = wsW2 + 16384;        // 2048 f16  = 4 KB (contiguous with wsW2)

  nerf_setup<<<36, 256, 0, stream>>>(W2, W3, wsW2, wsW3);
  nerf_main<<<16384 / 8, 512, 0, stream>>>(
      origins, dirs, W1, b1, b2, b3, wsW2, out);
}

// Round 10
// 102.075 us; speedup vs baseline: 1.5443x; 1.5443x over previous
//
#include <hip/hip_runtime.h>

// NeRF fused kernel for MI355X (gfx950) — round 15.
// Round 14 post-mortem: cross-backedge prefetch spilled AGAIN — but with
// VGPR_Count still 64: __launch_bounds__(512,4) is only a MINIMUM; the
// compiler targets ~85 regs (LDS allows 3 blocks/CU = 6 waves/SIMD) rounded
// down to a 64-granule and SPILLS overflow instead of growing. Any structure
// raising the live set across the ks3 backedge spills. In-wave pipelining is
// structurally unavailable (3rd confirmation: r9 unroll, r14 prefetch, r13
// setprio neutral).
// Round 15 = round-8 config EXACT (verified 102.6us: 36-block setup, LDS
// weights, rolled ks3, no rotation/setprio/prefetch) + bias-as-C:
// the ks2=0 MFMA takes C = b2 bias registers directly
//   (old: acc=bias via 32 v_mov, then mfma(wA0,hb0,acc);
//    new: acc = mfma(wA0,hb0,bias4) — same D=A*B+C op, BIT-IDENTICAL),
// deleting 32 VALU/iter = 128/wave (~8% of VALUBusy) at zero register and
// zero control-flow cost.
// Permutation identity (HW-verified rounds 4-14):
//   h2 feature(slot) = 32*quad + mt*4 + r  (phase-2 D)  =  32*quad + ks3*8 + j
//   (phase-3 B), so phase-2 output regs ARE phase-3 B-frags.

typedef _Float16 f16;
typedef __attribute__((ext_vector_type(2))) _Float16 h2v;
typedef __attribute__((ext_vector_type(8))) _Float16 half8;
typedef __attribute__((ext_vector_type(4))) float floatx4;

#define H 128
#define NS 64

static __device__ __forceinline__ h2v pkrtz(float a, float b) {
  return __builtin_bit_cast(h2v, __builtin_amdgcn_cvt_pkrtz(a, b));
}

// x += dpp_shifted(x) with 0-fill; CTRL/RM compile-time (builtin needs ICE).
template <int CTRL, int RM>
static __device__ __forceinline__ float dpp_add(float x) {
  int sh = __builtin_amdgcn_update_dpp(0, __builtin_bit_cast(int, x),
                                       CTRL, RM, 0xf, false);
  return x + __builtin_bit_cast(float, sh);
}

// Wave64 inclusive add-scan, pure VALU (classic gfx9 sequence).
static __device__ __forceinline__ float wave_iscan(float x) {
  x = dpp_add<0x111, 0xf>(x);   // row_shr:1
  x = dpp_add<0x112, 0xf>(x);   // row_shr:2
  x = dpp_add<0x114, 0xf>(x);   // row_shr:4
  x = dpp_add<0x118, 0xf>(x);   // row_shr:8
  x = dpp_add<0x142, 0xa>(x);   // row_bcast:15 -> rows 1,3
  x = dpp_add<0x143, 0xc>(x);   // row_bcast:31 -> rows 2,3
  return x;
}

// ---------------------------------------------------------------------------
// Setup (round-8 version verbatim — part of the 102.6us-proven config):
// W2 -> A-frags with permuted cols n = 32*(l16>>2) + mt*4 + (l16&3);
// W3 -> A-frags with matching permuted rows k3 = 32*(lane>>4) + ks*8 + j
// (cols padded to 16). 36 blocks x 256 threads, direct scattered gathers.
// ---------------------------------------------------------------------------
__global__ void nerf_setup(const float* __restrict__ W2, const float* __restrict__ W3,
                           f16* __restrict__ wsW2, f16* __restrict__ wsW3) {
  int t = blockIdx.x * blockDim.x + threadIdx.x;
  if (t < 8192) {                       // W2 frags
    int j2 = t & 3, lane = (t >> 2) & 63, mt = (t >> 8) & 7, ks = t >> 11;
    int l16 = lane & 15;
    int k = ks * 32 + ((lane >> 4) * 8) + 2 * j2;
    int n = 32 * (l16 >> 2) + mt * 4 + (l16 & 3);    // permuted column
    wsW2[2 * t]     = (f16)W2[k * H + n];
    wsW2[2 * t + 1] = (f16)W2[(k + 1) * H + n];
  } else if (t < 9216) {                // W3 frags (A-layout, permuted rows, padded)
    int u = t - 8192;
    int j2 = u & 3, lane = (u >> 2) & 63, ks = u >> 8;
    int c = lane & 15;
    int k3 = 32 * (lane >> 4) + ks * 8 + 2 * j2;     // permuted h2 feature
    wsW3[2 * u]     = (c < 4) ? (f16)W3[k3 * 4 + c]       : (f16)0.0f;
    wsW3[2 * u + 1] = (c < 4) ? (f16)W3[(k3 + 1) * 4 + c] : (f16)0.0f;
  }
}

// ---------------------------------------------------------------------------
// Main: block = 8 rays = 8 waves; wave = 1 ray = 64 points.
// One barrier (after LDS weight staging); no other cross-wave deps.
// ---------------------------------------------------------------------------
__global__ __launch_bounds__(512, 4) void nerf_main(
    const float* __restrict__ origins, const float* __restrict__ dirs,
    const float* __restrict__ W1, const float* __restrict__ b1,
    const float* __restrict__ b2, const float* __restrict__ b3,
    const f16* __restrict__ ws,          // wsW2 (32 KB) ++ wsW3 (4 KB)
    float* __restrict__ out)
{
  __shared__ __align__(16) half8 w_lds[2304];     // 36 KB: W2 frags [0..2047], W3 [2048..2303]
  __shared__ __align__(16) float b2_lds[H];       // 512 B
  __shared__ __align__(16) f16   popd[8][2][H];   // per-wave po/pd strips (4 KB)
  __shared__ __align__(16) float f_lds[8][64][4]; // render transpose (8 KB)

  const int t = threadIdx.x;
  const int w = t >> 6, lane = t & 63, quad = lane >> 4, l16 = lane & 15;
  const float delta = 4.0f / NS;       // near=2, far=6 baked
  const int ray = blockIdx.x * 8 + w;

  // ---- Stage weights into LDS (2304 x 16 B = 4.5 per thread) ----
  {
    const uint4* src = (const uint4*)ws;
    uint4* dst = (uint4*)w_lds;
    #pragma unroll
    for (int i = 0; i < 4; ++i) dst[t + i * 512] = src[t + i * 512];
    if (t < 256) dst[t + 2048] = src[t + 2048];
    if (t < 32)  ((float4*)b2_lds)[t] = ((const float4*)b2)[t];
  }

  // ---- po/pd: po[k] = o@W1[:,k]+b1[k], pd[k] = d@W1[:,k]; f16 to LDS ----
  {
    const float o0 = origins[ray*3], o1 = origins[ray*3+1], o2 = origins[ray*3+2];
    const float d0 = dirs[ray*3],    d1 = dirs[ray*3+1],    d2 = dirs[ray*3+2];
    const int k0 = lane * 2;
    const float2 wr0 = *(const float2*)&W1[0*H + k0];
    const float2 wr1 = *(const float2*)&W1[1*H + k0];
    const float2 wr2 = *(const float2*)&W1[2*H + k0];
    const float2 bb  = *(const float2*)&b1[k0];
    float poa = fmaf(o2, wr2.x, fmaf(o1, wr1.x, fmaf(o0, wr0.x, bb.x)));
    float pob = fmaf(o2, wr2.y, fmaf(o1, wr1.y, fmaf(o0, wr0.y, bb.y)));
    float pda = fmaf(d2, wr2.x, fmaf(d1, wr1.x, d0 * wr0.x));
    float pdb = fmaf(d2, wr2.y, fmaf(d1, wr1.y, d0 * wr0.y));
    h2v po2; po2[0] = (f16)poa; po2[1] = (f16)pob;
    h2v pd2; pd2[0] = (f16)pda; pd2[1] = (f16)pdb;
    *(h2v*)&popd[w][0][k0] = po2;
    *(h2v*)&popd[w][1][k0] = pd2;
  }

  // ---- hb precompute: hb[ks2][tr] = relu(po + m*pd), resident 64 VGPRs ----
  // m exact in f16 (multiple of 1/32); sample s = tr*16 + l16.
  half8 hb[4][4];
  {
    const half8 z8 = (half8)(f16)0.0f;
    half8 m8[4];
    #pragma unroll
    for (int tr = 0; tr < 4; ++tr)
      m8[tr] = (half8)(f16)(2.0f + (tr*16 + l16 + 0.5f) * delta);
    #pragma unroll
    for (int ks = 0; ks < 4; ++ks) {
      const half8 po8 = *(const half8*)&popd[w][0][ks*32 + quad*8];
      const half8 pd8 = *(const half8*)&popd[w][1][ks*32 + quad*8];
      #pragma unroll
      for (int tr = 0; tr < 4; ++tr)
        hb[ks][tr] = __builtin_elementwise_max(pd8 * m8[tr] + po8, z8);
    }
  }

  __syncthreads();                       // weights staged

  const half8* w2f = w_lds;              // 2048 frags
  const half8* w3f = w_lds + 2048;       // 256 frags
  const h2v z2 = (h2v)(f16)0.0f;

  // acc3 init = b3 broadcast (quad 0 rows are the only consumed ones; W3
  // cols >=4 are zero-padded so other quads are garbage-but-unused).
  floatx4 acc3[4];
  {
    const float4 b3v = *(const float4*)&b3[0];
    #pragma unroll
    for (int tr = 0; tr < 4; ++tr) {
      acc3[tr][0] = b3v.x; acc3[tr][1] = b3v.y;
      acc3[tr][2] = b3v.z; acc3[tr][3] = b3v.w;
    }
  }

  // ---- Fused phase 2+3, mt-pair outer, ROLLED (4 iters, reg-safe).
  // bias-as-C: ks2=0 MFMAs take C = b2 bias regs directly (bit-identical
  // to init-then-accumulate; deletes the 32-mov acc init per iteration). ----
  #pragma unroll 1
  for (int ks3 = 0; ks3 < 4; ++ks3) {
    const int mt0 = 2 * ks3, mt1 = mt0 + 1;
    // bias: acc[mt][tr][r] seeds from b2[32*quad + 4*mt + r] via MFMA C
    const floatx4 bA4 = *(const floatx4*)&b2_lds[quad*32 + ks3*8];
    const floatx4 bB4 = *(const floatx4*)&b2_lds[quad*32 + ks3*8 + 4];
    const half8 w3k = w3f[ks3*64 + lane];
    floatx4 accA[4], accB[4];
    // ks2 = 0: D = wA0*hb0 + bias (C operand shared across tr)
    {
      const half8 wA = w2f[mt0*64 + lane];
      const half8 wB = w2f[mt1*64 + lane];
      #pragma unroll
      for (int tr = 0; tr < 4; ++tr) {
        accA[tr] = __builtin_amdgcn_mfma_f32_16x16x32_f16(wA, hb[0][tr], bA4, 0, 0, 0);
        accB[tr] = __builtin_amdgcn_mfma_f32_16x16x32_f16(wB, hb[0][tr], bB4, 0, 0, 0);
      }
    }
    #pragma unroll
    for (int ks2 = 1; ks2 < 4; ++ks2) {
      const half8 wA = w2f[(ks2*8 + mt0)*64 + lane];
      const half8 wB = w2f[(ks2*8 + mt1)*64 + lane];
      #pragma unroll
      for (int tr = 0; tr < 4; ++tr) {
        accA[tr] = __builtin_amdgcn_mfma_f32_16x16x32_f16(wA, hb[ks2][tr], accA[tr], 0, 0, 0);
        accB[tr] = __builtin_amdgcn_mfma_f32_16x16x32_f16(wB, hb[ks2][tr], accB[tr], 0, 0, 0);
      }
    }
    // pack (bias already in acc) + phase-3 MFMA; b covers features
    // 32*quad + 8*ks3 + 0..7 matching W3's permuted rows.
    #pragma unroll
    for (int tr = 0; tr < 4; ++tr) {
      h2v c0 = __builtin_elementwise_max(pkrtz(accA[tr][0], accA[tr][1]), z2);
      h2v c1 = __builtin_elementwise_max(pkrtz(accA[tr][2], accA[tr][3]), z2);
      h2v c2 = __builtin_elementwise_max(pkrtz(accB[tr][0], accB[tr][1]), z2);
      h2v c3 = __builtin_elementwise_max(pkrtz(accB[tr][2], accB[tr][3]), z2);
      half8 b = { c0[0], c0[1], c1[0], c1[1], c2[0], c2[1], c3[0], c3[1] };
      acc3[tr] = __builtin_amdgcn_mfma_f32_16x16x32_f16(w3k, b, acc3[tr], 0, 0, 0);
    }
  }

  // D3: lane holds f[m = quad*4+r][point tr*16+l16]; quad 0 rows 0..3 are
  // (R,G,B,sigma), b3 already folded in. Transpose via tiny f_lds (same
  // wave, no barrier).
  if (quad == 0) {
    #pragma unroll
    for (int tr = 0; tr < 4; ++tr) {
      float4 fv;
      fv.x = acc3[tr][0]; fv.y = acc3[tr][1];
      fv.z = acc3[tr][2]; fv.w = acc3[tr][3];
      *(float4*)&f_lds[w][tr*16 + l16][0] = fv;      // ds_write_b128
    }
  }

  // ---- Phase 4: volume rendering, lane = sample; DPP scan, no bpermute ----
  {
    const float4 fv = *(const float4*)&f_lds[w][lane][0];
    const float sigma = fv.w;
    const float alpha = 1.0f - __expf(-sigma * delta);
    const float S  = wave_iscan(sigma);              // inclusive prefix
    const float T  = __expf(-delta * (S - sigma));   // exclusive transmittance
    const float wt = alpha * T;
    const float sr = wave_iscan(wt * fv.x);          // lane 63 = total
    const float sg = wave_iscan(wt * fv.y);
    const float sb = wave_iscan(wt * fv.z);
    if (lane == 63) {
      out[ray*3+0] = sr; out[ray*3+1] = sg; out[ray*3+2] = sb;
    }
  }
}

extern "C" void kernel_launch(void* const* d_in, const int* in_sizes, int n_in,
                              void* d_out, int out_size, void* d_ws, size_t ws_size,
                              hipStream_t stream) {
  const float* origins = (const float*)d_in[0];
  const float* dirs    = (const float*)d_in[1];
  const float* W1      = (const float*)d_in[2];
  const float* b1      = (const float*)d_in[3];
  const float* W2      = (const float*)d_in[4];
  const float* b2      = (const float*)d_in[5];
  const float* W3      = (const float*)d_in[6];
  const float* b3      = (const float*)d_in[7];
  float* out = (float*)d_out;

  f16* wsW2 = (f16*)d_ws;          // 16384 f16 = 32 KB
  f16* wsW3 = wsW2 + 16384;        // 2048 f16  = 4 KB (contiguous with wsW2)

  nerf_setup<<<36, 256, 0, stream>>>(W2, W3, wsW2, wsW3);
  nerf_main<<<16384 / 8, 512, 0, stream>>>(
      origins, dirs, W1, b1, b2, b3, wsW2, out);
}